// Round 6
// baseline (7557.219 us; speedup 1.0000x reference)
//
#include <hip/hip_runtime.h>

typedef unsigned short u16;
typedef unsigned int   u32;

#define V_ 780
#define N_ 50000
#define M_ 100001
#define K_ 6
#define H_ 256
#define B_ 64
#define DEPTH_ 6

__device__ __forceinline__ float b2f(u16 u){
  union { u32 i; float f; } x; x.i = ((u32)u) << 16; return x.f;
}
__device__ __forceinline__ u16 f2b(float f){
  union { float f; u32 i; } x; x.f = f;
  u32 r = x.i + 0x7fffu + ((x.i >> 16) & 1u);   // RNE
  return (u16)(r >> 16);
}
__device__ __forceinline__ float sigm(float x){ return 1.f/(1.f + __expf(-x)); }
__device__ __forceinline__ float tanh_(float x){
  x = fminf(fmaxf(x, -15.f), 15.f);
  float e = __expf(2.f*x);
  return (e - 1.f)/(e + 1.f);
}

// ---- Per-vocab tables in f32 (exact): emb@W1.T + bias for Wz,Wr(+bu),Wh,Wo; h1 closed form.
__global__ void k_tables(const float* __restrict__ emb,
    const float* __restrict__ Wz, const float* __restrict__ bz,
    const float* __restrict__ Wr, const float* __restrict__ bu,
    const float* __restrict__ Wh, const float* __restrict__ bh,
    const float* __restrict__ Wo, const float* __restrict__ bo,
    float* __restrict__ tWz, float* __restrict__ tWr,
    float* __restrict__ tWh, float* __restrict__ tWo, float* __restrict__ tH1){
  int v = blockIdx.x, j = threadIdx.x;
  __shared__ float e[H_];
  e[j] = emb[v*H_ + j];
  __syncthreads();
  const float* wz = Wz + j*(2*H_);
  const float* wr = Wr + j*H_;
  const float* wh = Wh + j*(2*H_);
  const float* wo = Wo + j*(2*H_);
  float az=0.f, ar=0.f, ah=0.f, ao=0.f;
  for (int i=0;i<H_;i+=4){
    float4 a;
    a = *(const float4*)(wz+i); az += e[i]*a.x + e[i+1]*a.y + e[i+2]*a.z + e[i+3]*a.w;
    a = *(const float4*)(wr+i); ar += e[i]*a.x + e[i+1]*a.y + e[i+2]*a.z + e[i+3]*a.w;
    a = *(const float4*)(wh+i); ah += e[i]*a.x + e[i+1]*a.y + e[i+2]*a.z + e[i+3]*a.w;
    a = *(const float4*)(wo+i); ao += e[i]*a.x + e[i+1]*a.y + e[i+2]*a.z + e[i+3]*a.w;
  }
  az += bz[j]; ar += bu[j]; ah += bh[j]; ao += bo[j];
  int idx = v*H_ + j;
  tWz[idx]=az; tWr[idx]=ar; tWh[idx]=ah; tWo[idx]=ao;
  tH1[idx] = sigm(az)*tanh_(ah);          // iteration-1 closed form (h=0)
}

// ---- Convert the three K-major 256x256 weight slices to bf16.
__global__ void k_convw(const float* __restrict__ Ur, const float* __restrict__ Wz,
                        const float* __restrict__ Wh,
                        u16* __restrict__ Urb, u16* __restrict__ Wzb, u16* __restrict__ Whb){
  int r = blockIdx.x, j = threadIdx.x;
  Urb[r*H_ + j] = f2b(Ur[r*H_ + j]);
  Wzb[r*H_ + j] = f2b(Wz[r*(2*H_) + H_ + j]);   // columns H..2H of Wz row r
  Whb[r*H_ + j] = f2b(Wh[r*(2*H_) + H_ + j]);
}

// ---- vmsg[m] = fnode[fmess[m]]; h(iter1) from table, masked at m==0. h is FLOAT32 (output dtype).
__global__ void k_init(const int* __restrict__ fnode, const int* __restrict__ fmess,
                       const float* __restrict__ tH1, int* __restrict__ vmsg,
                       float* __restrict__ h){
  int m = blockIdx.x, j = threadIdx.x;
  int v = fnode[fmess[m]];
  if (j == 0) vmsg[m] = v;
  h[(size_t)m*H_ + j] = (m == 0) ? 0.f : tH1[v*H_ + j];
}

// ---- Neighbor gather + reduce: sum_h and sum_gated (r = sigm(xr + hUr_nei)). h is f32.
__global__ void k_gather(const float* __restrict__ h, const u16* __restrict__ hUr,
                         const int* __restrict__ mg, const int* __restrict__ vmsg,
                         const float* __restrict__ tWr,
                         u16* __restrict__ sumh, u16* __restrict__ sumg){
  int m = blockIdx.x*2 + (threadIdx.x >> 7);
  if (m >= M_) return;
  int tj = (threadIdx.x & 127) * 2;
  int v = vmsg[m];
  float2 xr = *(const float2*)(tWr + v*H_ + tj);
  float s0=0.f, s1=0.f, g0=0.f, g1=0.f;
  #pragma unroll
  for (int k=0;k<K_;k++){
    int g = mg[m*K_ + k];
    float2 hv = *(const float2*)(h + (size_t)g*H_ + tj);
    u32 up = *(const u32*)(hUr + (size_t)g*H_ + tj);
    float u0 = b2f((u16)up), u1 = b2f((u16)(up>>16));
    s0 += hv.x; s1 += hv.y;
    g0 += sigm(xr.x+u0)*hv.x; g1 += sigm(xr.y+u1)*hv.y;
  }
  *(u32*)(sumh + (size_t)m*H_ + tj) = (u32)f2b(s0) | ((u32)f2b(s1)<<16);
  *(u32*)(sumg + (size_t)m*H_ + tj) = (u32)f2b(g0) | ((u32)f2b(g1)<<16);
}

// ---- VALU GEMM: C[m,n] = sum_k A[m,k] * W[n,k].  Block = 4 m-rows x 256 n-cols.
// AF32: A read as f32 (the h matrix). FUSED: GRU epilogue, C is f32 h (output).
template<bool FUSED, bool AF32>
__global__ __launch_bounds__(256) void k_gemm(
    const void* __restrict__ Av, const u16* __restrict__ W,
    void* __restrict__ Cv,
    const u16* __restrict__ zlin, const u16* __restrict__ sumh,
    const float* __restrict__ tWz, const float* __restrict__ tWh,
    const int* __restrict__ vmsg){
  __shared__ float la[4][H_];
  const int t  = threadIdx.x;
  const int mb = blockIdx.x*4;
  #pragma unroll
  for (int r=0;r<4;r++){
    int m = mb + r;
    float av = 0.f;
    if (m < M_){
      av = AF32 ? ((const float*)Av)[(size_t)m*H_ + t]
                : b2f(((const u16*)Av)[(size_t)m*H_ + t]);
    }
    la[r][t] = av;
  }
  __syncthreads();
  const int n = t;
  float ac0=0.f, ac1=0.f, ac2=0.f, ac3=0.f;
  for (int k=0;k<H_;k+=2){
    u32 wp = *(const u32*)(W + (size_t)n*H_ + k);
    float w0 = b2f((u16)wp), w1 = b2f((u16)(wp>>16));
    ac0 += la[0][k]*w0 + la[0][k+1]*w1;
    ac1 += la[1][k]*w0 + la[1][k+1]*w1;
    ac2 += la[2][k]*w0 + la[2][k+1]*w1;
    ac3 += la[3][k]*w0 + la[3][k+1]*w1;
  }
  float accs[4] = {ac0, ac1, ac2, ac3};
  #pragma unroll
  for (int r=0;r<4;r++){
    int m = mb + r;
    if (m >= M_) continue;
    float a = accs[r];
    if (FUSED){
      int v = vmsg[m];
      float z   = sigm(tWz[v*H_ + n] + b2f(zlin[(size_t)m*H_ + n]));
      float pre = tanh_(tWh[v*H_ + n] + a);
      float sh  = b2f(sumh[(size_t)m*H_ + n]);
      float o   = (m == 0) ? 0.f : (1.f - z)*sh + z*pre;
      ((float*)Cv)[(size_t)m*H_ + n] = o;          // h is f32 output
    } else {
      ((u16*)Cv)[(size_t)m*H_ + n] = f2b(a);       // bf16 intermediate
    }
  }
}

// ---- Readout: only B=64 scope rows are needed. h f32, out f32.
__global__ void k_final(const float* __restrict__ h, const int* __restrict__ ng,
                        const int* __restrict__ fnode, const int* __restrict__ scope,
                        const float* __restrict__ tWo, const float* __restrict__ Wo,
                        float* __restrict__ out){
  int b = blockIdx.x, j = threadIdx.x;
  int n = scope[b];
  __shared__ float mn[H_];
  float s = 0.f;
  #pragma unroll
  for (int k=0;k<K_;k++){
    int g = ng[n*K_ + k];
    s += h[(size_t)g*H_ + j];
  }
  mn[j] = s;
  __syncthreads();
  int v = fnode[n];
  float acc = tWo[v*H_ + j];
  const float* w = Wo + j*(2*H_) + H_;
  for (int i=0;i<H_;i+=4){
    float4 a = *(const float4*)(w+i);
    acc += mn[i]*a.x + mn[i+1]*a.y + mn[i+2]*a.z + mn[i+3]*a.w;
  }
  out[b*H_ + j] = fmaxf(acc, 0.f);
}

// ---- Guard signal: all-zero f32 output (absmax would equal max|ref| = 0.3086).
__global__ void k_zero(float* __restrict__ out, int n){
  int i = blockIdx.x*256 + threadIdx.x;
  int stride = gridDim.x*256;
  for (; i < n; i += stride) out[i] = 0.f;
}

extern "C" void kernel_launch(void* const* d_in, const int* in_sizes, int n_in,
                              void* d_out, int out_size, void* d_ws, size_t ws_size,
                              hipStream_t stream){
  const int* fnode      = (const int*)d_in[0];
  const int* fmess      = (const int*)d_in[1];
  const int* node_graph = (const int*)d_in[2];
  const int* mess_graph = (const int*)d_in[3];
  const int* scope_st   = (const int*)d_in[4];
  const float* emb = (const float*)d_in[5];
  const float* Wz  = (const float*)d_in[6];
  const float* bz  = (const float*)d_in[7];
  const float* Wr  = (const float*)d_in[8];
  const float* Ur  = (const float*)d_in[9];
  const float* bu  = (const float*)d_in[10];
  const float* Wh  = (const float*)d_in[11];
  const float* bh  = (const float*)d_in[12];
  const float* Wo  = (const float*)d_in[13];
  const float* bo  = (const float*)d_in[14];

  char* ws = (char*)d_ws;
  size_t off = 0;
  float* tWz = (float*)(ws + off); off += (size_t)V_*H_*4;
  float* tWr = (float*)(ws + off); off += (size_t)V_*H_*4;
  float* tWh = (float*)(ws + off); off += (size_t)V_*H_*4;
  float* tWo = (float*)(ws + off); off += (size_t)V_*H_*4;
  float* tH1 = (float*)(ws + off); off += (size_t)V_*H_*4;
  u16* Urb  = (u16*)(ws + off); off += (size_t)H_*H_*2;
  u16* Wzb  = (u16*)(ws + off); off += (size_t)H_*H_*2;
  u16* Whb  = (u16*)(ws + off); off += (size_t)H_*H_*2;
  int* vmsg = (int*)(ws + off); off += ((size_t)M_*4 + 511) & ~(size_t)511;
  u16* hUr  = (u16*)(ws + off); off += (size_t)M_*H_*2;   // doubles as zlin buffer
  u16* sumh = (u16*)(ws + off); off += (size_t)M_*H_*2;
  u16* sumg = (u16*)(ws + off); off += (size_t)M_*H_*2;

  if (ws_size < off){
    k_zero<<<2048, 256, 0, stream>>>((float*)d_out, out_size);
    return;
  }

  float* out = (float*)d_out;          // OUTPUT DTYPE IS FLOAT32 (reference returns f32)
  float* h   = out + (size_t)B_*H_;    // h (output 1) lives in d_out, f32

  const int GT = (M_ + 3)/4;           // 25001 blocks, 4 rows each

  k_tables<<<V_, H_, 0, stream>>>(emb, Wz, bz, Wr, bu, Wh, bh, Wo, bo,
                                  tWz, tWr, tWh, tWo, tH1);
  k_convw<<<H_, H_, 0, stream>>>(Ur, Wz, Wh, Urb, Wzb, Whb);
  k_init<<<M_, H_, 0, stream>>>(fnode, fmess, tH1, vmsg, h);

  for (int it = 0; it < DEPTH_-1; ++it){
    // hUr = h @ Ur.T           (A = h, f32 -> bf16 C)
    k_gemm<false,true ><<<GT, 256, 0, stream>>>(h, Urb, hUr,
                                                nullptr,nullptr,nullptr,nullptr,nullptr);
    // sum_h, sum_gated
    k_gather<<<(M_+1)/2, 256, 0, stream>>>(h, hUr, mess_graph, vmsg, tWr, sumh, sumg);
    // zlin = sum_h @ Wz2.T     (reuses hUr buffer)
    k_gemm<false,false><<<GT, 256, 0, stream>>>(sumh, Wzb, hUr,
                                                nullptr,nullptr,nullptr,nullptr,nullptr);
    // hlin = sum_g @ Wh2.T, fused GRU update -> h (f32)
    k_gemm<true ,false><<<GT, 256, 0, stream>>>(sumg, Whb, h,
                                                hUr, sumh, tWz, tWh, vmsg);
  }

  k_final<<<B_, H_, 0, stream>>>(h, node_graph, fnode, scope_st, tWo, Wo, out);
}

// Round 7
// 2148.598 us; speedup vs baseline: 3.5173x; 3.5173x over previous
//
#include <hip/hip_runtime.h>

typedef unsigned short u16;
typedef unsigned int   u32;
typedef short bf16x8 __attribute__((ext_vector_type(8)));
typedef float f32x4  __attribute__((ext_vector_type(4)));

#define V_ 780
#define N_ 50000
#define M_ 100001
#define K_ 6
#define H_ 256
#define B_ 64
#define DEPTH_ 6

__device__ __forceinline__ float b2f(u16 u){
  union { u32 i; float f; } x; x.i = ((u32)u) << 16; return x.f;
}
__device__ __forceinline__ u16 f2b(float f){
  union { float f; u32 i; } x; x.f = f;
  u32 r = x.i + 0x7fffu + ((x.i >> 16) & 1u);   // RNE
  return (u16)(r >> 16);
}
__device__ __forceinline__ float sigm(float x){ return 1.f/(1.f + __expf(-x)); }
__device__ __forceinline__ float tanh_(float x){
  x = fminf(fmaxf(x, -15.f), 15.f);
  float e = __expf(2.f*x);
  return (e - 1.f)/(e + 1.f);
}
__device__ __forceinline__ int swz(int r){ return (r + (r >> 2)) & 3; }

// ---- Per-vocab tables in f32 (exact): emb@W1.T + bias for Wz,Wr(+bu),Wh,Wo; h1 closed form.
__global__ void k_tables(const float* __restrict__ emb,
    const float* __restrict__ Wz, const float* __restrict__ bz,
    const float* __restrict__ Wr, const float* __restrict__ bu,
    const float* __restrict__ Wh, const float* __restrict__ bh,
    const float* __restrict__ Wo, const float* __restrict__ bo,
    float* __restrict__ tWz, float* __restrict__ tWr,
    float* __restrict__ tWh, float* __restrict__ tWo, float* __restrict__ tH1){
  int v = blockIdx.x, j = threadIdx.x;
  __shared__ float e[H_];
  e[j] = emb[v*H_ + j];
  __syncthreads();
  const float* wz = Wz + j*(2*H_);
  const float* wr = Wr + j*H_;
  const float* wh = Wh + j*(2*H_);
  const float* wo = Wo + j*(2*H_);
  float az=0.f, ar=0.f, ah=0.f, ao=0.f;
  for (int i=0;i<H_;i+=4){
    float4 a;
    a = *(const float4*)(wz+i); az += e[i]*a.x + e[i+1]*a.y + e[i+2]*a.z + e[i+3]*a.w;
    a = *(const float4*)(wr+i); ar += e[i]*a.x + e[i+1]*a.y + e[i+2]*a.z + e[i+3]*a.w;
    a = *(const float4*)(wh+i); ah += e[i]*a.x + e[i+1]*a.y + e[i+2]*a.z + e[i+3]*a.w;
    a = *(const float4*)(wo+i); ao += e[i]*a.x + e[i+1]*a.y + e[i+2]*a.z + e[i+3]*a.w;
  }
  az += bz[j]; ar += bu[j]; ah += bh[j]; ao += bo[j];
  int idx = v*H_ + j;
  tWz[idx]=az; tWr[idx]=ar; tWh[idx]=ah; tWo[idx]=ao;
  tH1[idx] = sigm(az)*tanh_(ah);          // iteration-1 closed form (h=0)
}

// ---- Convert the three K-major 256x256 weight slices to bf16.
__global__ void k_convw(const float* __restrict__ Ur, const float* __restrict__ Wz,
                        const float* __restrict__ Wh,
                        u16* __restrict__ Urb, u16* __restrict__ Wzb, u16* __restrict__ Whb){
  int r = blockIdx.x, j = threadIdx.x;
  Urb[r*H_ + j] = f2b(Ur[r*H_ + j]);
  Wzb[r*H_ + j] = f2b(Wz[r*(2*H_) + H_ + j]);   // columns H..2H of Wz row r
  Whb[r*H_ + j] = f2b(Wh[r*(2*H_) + H_ + j]);
}

// ---- vmsg[m] = fnode[fmess[m]]; h(iter1) from table, masked at m==0. h is f32 (output dtype).
__global__ void k_init(const int* __restrict__ fnode, const int* __restrict__ fmess,
                       const float* __restrict__ tH1, int* __restrict__ vmsg,
                       float* __restrict__ h){
  int m = blockIdx.x, j = threadIdx.x;
  int v = fnode[fmess[m]];
  if (j == 0) vmsg[m] = v;
  h[(size_t)m*H_ + j] = (m == 0) ? 0.f : tH1[v*H_ + j];
}

// ---- Neighbor gather + reduce: sum_h and sum_gated (r = sigm(xr + hUr_nei)). h is f32.
__global__ void k_gather(const float* __restrict__ h, const u16* __restrict__ hUr,
                         const int* __restrict__ mg, const int* __restrict__ vmsg,
                         const float* __restrict__ tWr,
                         u16* __restrict__ sumh, u16* __restrict__ sumg){
  int m = blockIdx.x*2 + (threadIdx.x >> 7);
  if (m >= M_) return;
  int tj = (threadIdx.x & 127) * 2;
  int v = vmsg[m];
  float2 xr = *(const float2*)(tWr + v*H_ + tj);
  float s0=0.f, s1=0.f, g0=0.f, g1=0.f;
  #pragma unroll
  for (int k=0;k<K_;k++){
    int g = mg[m*K_ + k];
    float2 hv = *(const float2*)(h + (size_t)g*H_ + tj);
    u32 up = *(const u32*)(hUr + (size_t)g*H_ + tj);
    float u0 = b2f((u16)up), u1 = b2f((u16)(up>>16));
    s0 += hv.x; s1 += hv.y;
    g0 += sigm(xr.x+u0)*hv.x; g1 += sigm(xr.y+u1)*hv.y;
  }
  *(u32*)(sumh + (size_t)m*H_ + tj) = (u32)f2b(s0) | ((u32)f2b(s1)<<16);
  *(u32*)(sumg + (size_t)m*H_ + tj) = (u32)f2b(g0) | ((u32)f2b(g1)<<16);
}

// ---- MFMA GEMM: C[m,n] = sum_k A[m,k]*W[n,k]. 128x128 tile, BK=32, XOR-swizzled LDS.
// AF32: A is f32 (h), converted to bf16 during staging. FUSED: GRU epilogue -> f32 h.
// Correctness of this structure was established R2-R5 (bit-identical to VALU GEMM).
template<bool FUSED, bool AF32>
__global__ __launch_bounds__(256,2) void k_gemm(
    const void* __restrict__ Av, const u16* __restrict__ W,
    void* __restrict__ Cv,
    const u16* __restrict__ zlin, const u16* __restrict__ sumh,
    const float* __restrict__ tWz, const float* __restrict__ tWh,
    const int* __restrict__ vmsg){
  __shared__ __align__(16) u16 lA[128*32];
  __shared__ __align__(16) u16 lB[128*32];
  const int t    = threadIdx.x;
  const int m0   = (blockIdx.x >> 1) * 128;
  const int n0   = (blockIdx.x & 1) * 128;
  const int lane = t & 63, wave = t >> 6;
  const int wrow = wave >> 1, wcol = wave & 1;
  const int l16  = lane & 15, kc8 = lane >> 4;

  f32x4 acc[4][4];
  #pragma unroll
  for (int r=0;r<4;r++)
    #pragma unroll
    for (int c=0;c<4;c++)
      #pragma unroll
      for (int q=0;q<4;q++) acc[r][c][q] = 0.f;

  for (int k0=0; k0<H_; k0+=32){
    __syncthreads();
    #pragma unroll
    for (int p=0;p<2;p++){
      int ch  = t + 256*p;            // 512 16B-chunks per tile
      int row = ch >> 2, kc = ch & 3;
      int cc  = kc ^ swz(row);        // XOR swizzle: bank-even b128 access, no pad
      int gm  = m0 + row;
      uint4 va = make_uint4(0u,0u,0u,0u);
      if (gm < M_){
        if (AF32){
          const float* ap = (const float*)Av + (size_t)gm*H_ + k0 + kc*8;
          float4 f0 = *(const float4*)(ap);
          float4 f1 = *(const float4*)(ap+4);
          va.x = (u32)f2b(f0.x) | ((u32)f2b(f0.y)<<16);
          va.y = (u32)f2b(f0.z) | ((u32)f2b(f0.w)<<16);
          va.z = (u32)f2b(f1.x) | ((u32)f2b(f1.y)<<16);
          va.w = (u32)f2b(f1.z) | ((u32)f2b(f1.w)<<16);
        } else {
          va = *(const uint4*)((const u16*)Av + (size_t)gm*H_ + k0 + kc*8);
        }
      }
      *(uint4*)(&lA[row*32 + cc*8]) = va;
      uint4 vb = *(const uint4*)(W + (size_t)(n0+row)*H_ + k0 + kc*8);
      *(uint4*)(&lB[row*32 + cc*8]) = vb;
    }
    __syncthreads();
    bf16x8 aF[4], bF[4];
    #pragma unroll
    for (int r=0;r<4;r++){
      int row = wrow*64 + r*16 + l16;
      aF[r] = *(const bf16x8*)(&lA[row*32 + (kc8 ^ swz(row))*8]);
    }
    #pragma unroll
    for (int c=0;c<4;c++){
      int row = wcol*64 + c*16 + l16;
      bF[c] = *(const bf16x8*)(&lB[row*32 + (kc8 ^ swz(row))*8]);
    }
    #pragma unroll
    for (int r=0;r<4;r++)
      #pragma unroll
      for (int c=0;c<4;c++)
        acc[r][c] = __builtin_amdgcn_mfma_f32_16x16x32_bf16(aF[r], bF[c], acc[r][c], 0,0,0);
  }

  #pragma unroll
  for (int r=0;r<4;r++){
    #pragma unroll
    for (int c=0;c<4;c++){
      int mb = m0 + wrow*64 + r*16 + kc8*4;     // C/D: row=(lane>>4)*4+reg
      int n  = n0 + wcol*64 + c*16 + l16;       //      col=lane&15
      #pragma unroll
      for (int q=0;q<4;q++){
        int m = mb + q;
        if (m < M_){
          float a = acc[r][c][q];
          if (FUSED){
            int v = vmsg[m];
            float z   = sigm(tWz[v*H_ + n] + b2f(zlin[(size_t)m*H_ + n]));
            float pre = tanh_(tWh[v*H_ + n] + a);
            float sh  = b2f(sumh[(size_t)m*H_ + n]);
            float o   = (m == 0) ? 0.f : (1.f - z)*sh + z*pre;
            ((float*)Cv)[(size_t)m*H_ + n] = o;          // h is f32 output
          } else {
            ((u16*)Cv)[(size_t)m*H_ + n] = f2b(a);       // bf16 intermediate
          }
        }
      }
    }
  }
}

// ---- Readout: only B=64 scope rows are needed. h f32, out f32.
__global__ void k_final(const float* __restrict__ h, const int* __restrict__ ng,
                        const int* __restrict__ fnode, const int* __restrict__ scope,
                        const float* __restrict__ tWo, const float* __restrict__ Wo,
                        float* __restrict__ out){
  int b = blockIdx.x, j = threadIdx.x;
  int n = scope[b];
  __shared__ float mn[H_];
  float s = 0.f;
  #pragma unroll
  for (int k=0;k<K_;k++){
    int g = ng[n*K_ + k];
    s += h[(size_t)g*H_ + j];
  }
  mn[j] = s;
  __syncthreads();
  int v = fnode[n];
  float acc = tWo[v*H_ + j];
  const float* w = Wo + j*(2*H_) + H_;
  for (int i=0;i<H_;i+=4){
    float4 a = *(const float4*)(w+i);
    acc += mn[i]*a.x + mn[i+1]*a.y + mn[i+2]*a.z + mn[i+3]*a.w;
  }
  out[b*H_ + j] = fmaxf(acc, 0.f);
}

// ---- Guard signal: all-zero f32 output.
__global__ void k_zero(float* __restrict__ out, int n){
  int i = blockIdx.x*256 + threadIdx.x;
  int stride = gridDim.x*256;
  for (; i < n; i += stride) out[i] = 0.f;
}

extern "C" void kernel_launch(void* const* d_in, const int* in_sizes, int n_in,
                              void* d_out, int out_size, void* d_ws, size_t ws_size,
                              hipStream_t stream){
  const int* fnode      = (const int*)d_in[0];
  const int* fmess      = (const int*)d_in[1];
  const int* node_graph = (const int*)d_in[2];
  const int* mess_graph = (const int*)d_in[3];
  const int* scope_st   = (const int*)d_in[4];
  const float* emb = (const float*)d_in[5];
  const float* Wz  = (const float*)d_in[6];
  const float* bz  = (const float*)d_in[7];
  const float* Wr  = (const float*)d_in[8];
  const float* Ur  = (const float*)d_in[9];
  const float* bu  = (const float*)d_in[10];
  const float* Wh  = (const float*)d_in[11];
  const float* bh  = (const float*)d_in[12];
  const float* Wo  = (const float*)d_in[13];
  const float* bo  = (const float*)d_in[14];

  char* ws = (char*)d_ws;
  size_t off = 0;
  float* tWz = (float*)(ws + off); off += (size_t)V_*H_*4;
  float* tWr = (float*)(ws + off); off += (size_t)V_*H_*4;
  float* tWh = (float*)(ws + off); off += (size_t)V_*H_*4;
  float* tWo = (float*)(ws + off); off += (size_t)V_*H_*4;
  float* tH1 = (float*)(ws + off); off += (size_t)V_*H_*4;
  u16* Urb  = (u16*)(ws + off); off += (size_t)H_*H_*2;
  u16* Wzb  = (u16*)(ws + off); off += (size_t)H_*H_*2;
  u16* Whb  = (u16*)(ws + off); off += (size_t)H_*H_*2;
  int* vmsg = (int*)(ws + off); off += ((size_t)M_*4 + 511) & ~(size_t)511;
  u16* hUr  = (u16*)(ws + off); off += (size_t)M_*H_*2;   // doubles as zlin buffer
  u16* sumh = (u16*)(ws + off); off += (size_t)M_*H_*2;
  u16* sumg = (u16*)(ws + off); off += (size_t)M_*H_*2;

  if (ws_size < off){
    k_zero<<<2048, 256, 0, stream>>>((float*)d_out, out_size);
    return;
  }

  float* out = (float*)d_out;          // output dtype f32 (established R6)
  float* h   = out + (size_t)B_*H_;    // h (output 1) lives in d_out, f32

  const int MT = (M_ + 127)/128;       // 782 row tiles
  const int GG = 2*MT;                 // x2 col tiles

  k_tables<<<V_, H_, 0, stream>>>(emb, Wz, bz, Wr, bu, Wh, bh, Wo, bo,
                                  tWz, tWr, tWh, tWo, tH1);
  k_convw<<<H_, H_, 0, stream>>>(Ur, Wz, Wh, Urb, Wzb, Whb);
  k_init<<<M_, H_, 0, stream>>>(fnode, fmess, tH1, vmsg, h);

  for (int it = 0; it < DEPTH_-1; ++it){
    // hUr = h @ Ur.T           (A = h f32 -> staged bf16; C bf16)
    k_gemm<false,true ><<<GG, 256, 0, stream>>>(h, Urb, hUr,
                                                nullptr,nullptr,nullptr,nullptr,nullptr);
    // sum_h, sum_gated
    k_gather<<<(M_+1)/2, 256, 0, stream>>>(h, hUr, mess_graph, vmsg, tWr, sumh, sumg);
    // zlin = sum_h @ Wz2.T     (reuses hUr buffer)
    k_gemm<false,false><<<GG, 256, 0, stream>>>(sumh, Wzb, hUr,
                                                nullptr,nullptr,nullptr,nullptr,nullptr);
    // hlin = sum_g @ Wh2.T, fused GRU update -> h (f32)
    k_gemm<true ,false><<<GG, 256, 0, stream>>>(sumg, Whb, h,
                                                hUr, sumh, tWz, tWh, vmsg);
  }

  k_final<<<B_, H_, 0, stream>>>(h, node_graph, fnode, scope_st, tWo, Wo, out);
}

// Round 8
// 1832.082 us; speedup vs baseline: 4.1249x; 1.1728x over previous
//
#include <hip/hip_runtime.h>

typedef unsigned short u16;
typedef unsigned int   u32;
typedef short bf16x8 __attribute__((ext_vector_type(8)));
typedef float f32x4  __attribute__((ext_vector_type(4)));

#define V_ 780
#define N_ 50000
#define M_ 100001
#define K_ 6
#define H_ 256
#define B_ 64
#define DEPTH_ 6

__device__ __forceinline__ float b2f(u16 u){
  union { u32 i; float f; } x; x.i = ((u32)u) << 16; return x.f;
}
__device__ __forceinline__ u16 f2b(float f){
  union { float f; u32 i; } x; x.f = f;
  u32 r = x.i + 0x7fffu + ((x.i >> 16) & 1u);   // RNE
  return (u16)(r >> 16);
}
__device__ __forceinline__ float sigm(float x){ return 1.f/(1.f + __expf(-x)); }
__device__ __forceinline__ float tanh_(float x){
  x = fminf(fmaxf(x, -15.f), 15.f);
  float e = __expf(2.f*x);
  return (e - 1.f)/(e + 1.f);
}
__device__ __forceinline__ int swz(int r){ return (r + (r >> 2)) & 3; }

// ---- Per-vocab tables, f32-exact. Grid (V, 4): block = (vocab v, matrix q).
// 4x the parallelism of the fused version; each thread one 256-dot with 2-way ILP.
__global__ void k_tables(const float* __restrict__ emb,
    const float* __restrict__ Wz, const float* __restrict__ bz,
    const float* __restrict__ Wr, const float* __restrict__ bu,
    const float* __restrict__ Wh, const float* __restrict__ bh,
    const float* __restrict__ Wo, const float* __restrict__ bo,
    float* __restrict__ tWz, float* __restrict__ tWr,
    float* __restrict__ tWh, float* __restrict__ tWo){
  int v = blockIdx.x, q = blockIdx.y, j = threadIdx.x;
  __shared__ float e[H_];
  e[j] = emb[v*H_ + j];
  __syncthreads();
  const float* w; const float* b; float* o; int ld;
  if      (q == 0){ w = Wz; b = bz; o = tWz; ld = 2*H_; }
  else if (q == 1){ w = Wr; b = bu; o = tWr; ld = H_;   }
  else if (q == 2){ w = Wh; b = bh; o = tWh; ld = 2*H_; }
  else            { w = Wo; b = bo; o = tWo; ld = 2*H_; }
  const float* wr = w + (size_t)j*ld;
  float a0 = 0.f, a1 = 0.f;
  #pragma unroll 4
  for (int i = 0; i < H_; i += 8){
    float4 x = *(const float4*)(wr + i);
    float4 y = *(const float4*)(wr + i + 4);
    a0 += e[i  ]*x.x + e[i+1]*x.y + e[i+2]*x.z + e[i+3]*x.w;
    a1 += e[i+4]*y.x + e[i+5]*y.y + e[i+6]*y.z + e[i+7]*y.w;
  }
  o[v*H_ + j] = a0 + a1 + b[j];
}

// ---- Convert the three K-major 256x256 weight slices to bf16.
__global__ void k_convw(const float* __restrict__ Ur, const float* __restrict__ Wz,
                        const float* __restrict__ Wh,
                        u16* __restrict__ Urb, u16* __restrict__ Wzb, u16* __restrict__ Whb){
  int r = blockIdx.x, j = threadIdx.x;
  Urb[r*H_ + j] = f2b(Ur[r*H_ + j]);
  Wzb[r*H_ + j] = f2b(Wz[r*(2*H_) + H_ + j]);   // columns H..2H of Wz row r
  Whb[r*H_ + j] = f2b(Wh[r*(2*H_) + H_ + j]);
}

// ---- vmsg[m] = fnode[fmess[m]]; h1 = sigm(z)*tanh(h) closed form (h0=0), bf16, masked at m==0.
__global__ void k_init(const int* __restrict__ fnode, const int* __restrict__ fmess,
                       const float* __restrict__ tWz, const float* __restrict__ tWh,
                       int* __restrict__ vmsg, u16* __restrict__ hb){
  int m = blockIdx.x, j = threadIdx.x;
  int v = fnode[fmess[m]];
  if (j == 0) vmsg[m] = v;
  float val = (m == 0) ? 0.f : sigm(tWz[v*H_ + j])*tanh_(tWh[v*H_ + j]);
  hb[(size_t)m*H_ + j] = f2b(val);
}

// ---- Neighbor gather + reduce from bf16 h: sum_h and sum_gated (r = sigm(xr + hUr_nei)).
__global__ void k_gather(const u16* __restrict__ hb, const u16* __restrict__ hUr,
                         const int* __restrict__ mg, const int* __restrict__ vmsg,
                         const float* __restrict__ tWr,
                         u16* __restrict__ sumh, u16* __restrict__ sumg){
  int m = blockIdx.x*2 + (threadIdx.x >> 7);
  if (m >= M_) return;
  int tj = (threadIdx.x & 127) * 2;
  int v = vmsg[m];
  float2 xr = *(const float2*)(tWr + v*H_ + tj);
  float s0=0.f, s1=0.f, g0=0.f, g1=0.f;
  #pragma unroll
  for (int k=0;k<K_;k++){
    int g = mg[m*K_ + k];
    u32 hp = *(const u32*)(hb  + (size_t)g*H_ + tj);
    u32 up = *(const u32*)(hUr + (size_t)g*H_ + tj);
    float h0 = b2f((u16)hp), h1 = b2f((u16)(hp>>16));
    float u0 = b2f((u16)up), u1 = b2f((u16)(up>>16));
    s0 += h0; s1 += h1;
    g0 += sigm(xr.x+u0)*h0; g1 += sigm(xr.y+u1)*h1;
  }
  *(u32*)(sumh + (size_t)m*H_ + tj) = (u32)f2b(s0) | ((u32)f2b(s1)<<16);
  *(u32*)(sumg + (size_t)m*H_ + tj) = (u32)f2b(g0) | ((u32)f2b(g1)<<16);
}

// ---- MFMA GEMM: C[m,n] = sum_k A[m,k]*W[n,k]. 128x128 tile, BK=32, XOR-swizzled LDS.
// A is bf16. FUSED: GRU epilogue; F32OUT selects f32 h (final iter) vs bf16 hb.
template<bool FUSED, bool F32OUT>
__global__ __launch_bounds__(256,2) void k_gemm(
    const u16* __restrict__ A, const u16* __restrict__ W,
    void* __restrict__ Cv,
    const u16* __restrict__ zlin, const u16* __restrict__ sumh,
    const float* __restrict__ tWz, const float* __restrict__ tWh,
    const int* __restrict__ vmsg){
  __shared__ __align__(16) u16 lA[128*32];
  __shared__ __align__(16) u16 lB[128*32];
  const int t    = threadIdx.x;
  const int m0   = (blockIdx.x >> 1) * 128;
  const int n0   = (blockIdx.x & 1) * 128;
  const int lane = t & 63, wave = t >> 6;
  const int wrow = wave >> 1, wcol = wave & 1;
  const int l16  = lane & 15, kc8 = lane >> 4;

  f32x4 acc[4][4];
  #pragma unroll
  for (int r=0;r<4;r++)
    #pragma unroll
    for (int c=0;c<4;c++)
      #pragma unroll
      for (int q=0;q<4;q++) acc[r][c][q] = 0.f;

  for (int k0=0; k0<H_; k0+=32){
    __syncthreads();
    #pragma unroll
    for (int p=0;p<2;p++){
      int ch  = t + 256*p;            // 512 16B-chunks per tile
      int row = ch >> 2, kc = ch & 3;
      int cc  = kc ^ swz(row);        // XOR swizzle: bank-even b128 access, no pad
      int gm  = m0 + row;
      uint4 va = (gm < M_) ? *(const uint4*)(A + (size_t)gm*H_ + k0 + kc*8)
                           : make_uint4(0u,0u,0u,0u);
      *(uint4*)(&lA[row*32 + cc*8]) = va;
      uint4 vb = *(const uint4*)(W + (size_t)(n0+row)*H_ + k0 + kc*8);
      *(uint4*)(&lB[row*32 + cc*8]) = vb;
    }
    __syncthreads();
    bf16x8 aF[4], bF[4];
    #pragma unroll
    for (int r=0;r<4;r++){
      int row = wrow*64 + r*16 + l16;
      aF[r] = *(const bf16x8*)(&lA[row*32 + (kc8 ^ swz(row))*8]);
    }
    #pragma unroll
    for (int c=0;c<4;c++){
      int row = wcol*64 + c*16 + l16;
      bF[c] = *(const bf16x8*)(&lB[row*32 + (kc8 ^ swz(row))*8]);
    }
    #pragma unroll
    for (int r=0;r<4;r++)
      #pragma unroll
      for (int c=0;c<4;c++)
        acc[r][c] = __builtin_amdgcn_mfma_f32_16x16x32_bf16(aF[r], bF[c], acc[r][c], 0,0,0);
  }

  #pragma unroll
  for (int r=0;r<4;r++){
    #pragma unroll
    for (int c=0;c<4;c++){
      int mb = m0 + wrow*64 + r*16 + kc8*4;     // C/D: row=(lane>>4)*4+reg
      int n  = n0 + wcol*64 + c*16 + l16;       //      col=lane&15
      #pragma unroll
      for (int q=0;q<4;q++){
        int m = mb + q;
        if (m < M_){
          float a = acc[r][c][q];
          if (FUSED){
            int v = vmsg[m];
            float z   = sigm(tWz[v*H_ + n] + b2f(zlin[(size_t)m*H_ + n]));
            float pre = tanh_(tWh[v*H_ + n] + a);
            float sh  = b2f(sumh[(size_t)m*H_ + n]);
            float o   = (m == 0) ? 0.f : (1.f - z)*sh + z*pre;
            if (F32OUT) ((float*)Cv)[(size_t)m*H_ + n] = o;   // final iter: f32 h
            else        ((u16*)Cv)[(size_t)m*H_ + n] = f2b(o);// mid iters: bf16 hb
          } else {
            ((u16*)Cv)[(size_t)m*H_ + n] = f2b(a);
          }
        }
      }
    }
  }
}

// ---- Readout: only B=64 scope rows are needed. h f32 (final), out f32.
__global__ void k_final(const float* __restrict__ h, const int* __restrict__ ng,
                        const int* __restrict__ fnode, const int* __restrict__ scope,
                        const float* __restrict__ tWo, const float* __restrict__ Wo,
                        float* __restrict__ out){
  int b = blockIdx.x, j = threadIdx.x;
  int n = scope[b];
  __shared__ float mn[H_];
  float s = 0.f;
  #pragma unroll
  for (int k=0;k<K_;k++){
    int g = ng[n*K_ + k];
    s += h[(size_t)g*H_ + j];
  }
  mn[j] = s;
  __syncthreads();
  int v = fnode[n];
  float acc = tWo[v*H_ + j];
  const float* w = Wo + j*(2*H_) + H_;
  for (int i=0;i<H_;i+=4){
    float4 a = *(const float4*)(w+i);
    acc += mn[i]*a.x + mn[i+1]*a.y + mn[i+2]*a.z + mn[i+3]*a.w;
  }
  out[b*H_ + j] = fmaxf(acc, 0.f);
}

// ---- Guard signal: all-zero f32 output.
__global__ void k_zero(float* __restrict__ out, int n){
  int i = blockIdx.x*256 + threadIdx.x;
  int stride = gridDim.x*256;
  for (; i < n; i += stride) out[i] = 0.f;
}

extern "C" void kernel_launch(void* const* d_in, const int* in_sizes, int n_in,
                              void* d_out, int out_size, void* d_ws, size_t ws_size,
                              hipStream_t stream){
  const int* fnode      = (const int*)d_in[0];
  const int* fmess      = (const int*)d_in[1];
  const int* node_graph = (const int*)d_in[2];
  const int* mess_graph = (const int*)d_in[3];
  const int* scope_st   = (const int*)d_in[4];
  const float* emb = (const float*)d_in[5];
  const float* Wz  = (const float*)d_in[6];
  const float* bz  = (const float*)d_in[7];
  const float* Wr  = (const float*)d_in[8];
  const float* Ur  = (const float*)d_in[9];
  const float* bu  = (const float*)d_in[10];
  const float* Wh  = (const float*)d_in[11];
  const float* bh  = (const float*)d_in[12];
  const float* Wo  = (const float*)d_in[13];
  const float* bo  = (const float*)d_in[14];

  char* ws = (char*)d_ws;
  size_t off = 0;
  float* tWz = (float*)(ws + off); off += (size_t)V_*H_*4;
  float* tWr = (float*)(ws + off); off += (size_t)V_*H_*4;
  float* tWh = (float*)(ws + off); off += (size_t)V_*H_*4;
  float* tWo = (float*)(ws + off); off += (size_t)V_*H_*4;
  u16* Urb  = (u16*)(ws + off); off += (size_t)H_*H_*2;
  u16* Wzb  = (u16*)(ws + off); off += (size_t)H_*H_*2;
  u16* Whb  = (u16*)(ws + off); off += (size_t)H_*H_*2;
  int* vmsg = (int*)(ws + off); off += ((size_t)M_*4 + 511) & ~(size_t)511;
  u16* hUr  = (u16*)(ws + off); off += (size_t)M_*H_*2;   // doubles as zlin buffer
  u16* sumh = (u16*)(ws + off); off += (size_t)M_*H_*2;
  u16* sumg = (u16*)(ws + off); off += (size_t)M_*H_*2;

  if (ws_size < off){
    k_zero<<<2048, 256, 0, stream>>>((float*)d_out, out_size);
    return;
  }

  float* out = (float*)d_out;          // output dtype f32 (established R6)
  float* h   = out + (size_t)B_*H_;    // h (output 1) lives in d_out, f32
  u16*   hb  = (u16*)h;                // bf16 shadow of h DURING iterations (front
                                       // half of the h region; final iter overwrites f32)

  const int MT = (M_ + 127)/128;       // 782 row tiles
  const int GG = 2*MT;                 // x2 col tiles

  k_tables<<<dim3(V_,4), H_, 0, stream>>>(emb, Wz, bz, Wr, bu, Wh, bh, Wo, bo,
                                          tWz, tWr, tWh, tWo);
  k_convw<<<H_, H_, 0, stream>>>(Ur, Wz, Wh, Urb, Wzb, Whb);
  k_init<<<M_, H_, 0, stream>>>(fnode, fmess, tWz, tWh, vmsg, hb);

  for (int it = 0; it < DEPTH_-1; ++it){
    // hUr = h @ Ur.T           (A = hb bf16; C bf16)
    k_gemm<false,false><<<GG, 256, 0, stream>>>(hb, Urb, hUr,
                                                nullptr,nullptr,nullptr,nullptr,nullptr);
    // sum_h, sum_gated (reads bf16 hb)
    k_gather<<<(M_+1)/2, 256, 0, stream>>>(hb, hUr, mess_graph, vmsg, tWr, sumh, sumg);
    // zlin = sum_h @ Wz2.T     (reuses hUr buffer)
    k_gemm<false,false><<<GG, 256, 0, stream>>>(sumh, Wzb, hUr,
                                                nullptr,nullptr,nullptr,nullptr,nullptr);
    // hlin = sum_g @ Wh2.T, fused GRU update; mid iters -> bf16 hb, final -> f32 h
    if (it < DEPTH_-2)
      k_gemm<true,false><<<GG, 256, 0, stream>>>(sumg, Whb, hb,
                                                 hUr, sumh, tWz, tWh, vmsg);
    else
      k_gemm<true,true ><<<GG, 256, 0, stream>>>(sumg, Whb, h,
                                                 hUr, sumh, tWz, tWh, vmsg);
  }

  k_final<<<B_, H_, 0, stream>>>(h, node_graph, fnode, scope_st, tWo, Wo, out);
}

// Round 9
// 1749.083 us; speedup vs baseline: 4.3207x; 1.0475x over previous
//
#include <hip/hip_runtime.h>

typedef unsigned short u16;
typedef unsigned int   u32;
typedef short bf16x8 __attribute__((ext_vector_type(8)));
typedef float f32x4  __attribute__((ext_vector_type(4)));

#define V_ 780
#define N_ 50000
#define M_ 100001
#define K_ 6
#define H_ 256
#define B_ 64
#define DEPTH_ 6

__device__ __forceinline__ float b2f(u16 u){
  union { u32 i; float f; } x; x.i = ((u32)u) << 16; return x.f;
}
__device__ __forceinline__ u16 f2b(float f){
  union { float f; u32 i; } x; x.f = f;
  u32 r = x.i + 0x7fffu + ((x.i >> 16) & 1u);   // RNE
  return (u16)(r >> 16);
}
__device__ __forceinline__ float sigm(float x){ return 1.f/(1.f + __expf(-x)); }
__device__ __forceinline__ float tanh_(float x){
  x = fminf(fmaxf(x, -15.f), 15.f);
  float e = __expf(2.f*x);
  return (e - 1.f)/(e + 1.f);
}
__device__ __forceinline__ int swz(int r){ return (r + (r >> 2)) & 3; }

// ---- Per-vocab tables, f32-exact. Grid (V, 4): block = (vocab v, matrix q).
__global__ void k_tables(const float* __restrict__ emb,
    const float* __restrict__ Wz, const float* __restrict__ bz,
    const float* __restrict__ Wr, const float* __restrict__ bu,
    const float* __restrict__ Wh, const float* __restrict__ bh,
    const float* __restrict__ Wo, const float* __restrict__ bo,
    float* __restrict__ tWz, float* __restrict__ tWr,
    float* __restrict__ tWh, float* __restrict__ tWo){
  int v = blockIdx.x, q = blockIdx.y, j = threadIdx.x;
  __shared__ float e[H_];
  e[j] = emb[v*H_ + j];
  __syncthreads();
  const float* w; const float* b; float* o; int ld;
  if      (q == 0){ w = Wz; b = bz; o = tWz; ld = 2*H_; }
  else if (q == 1){ w = Wr; b = bu; o = tWr; ld = H_;   }
  else if (q == 2){ w = Wh; b = bh; o = tWh; ld = 2*H_; }
  else            { w = Wo; b = bo; o = tWo; ld = 2*H_; }
  const float* wr = w + (size_t)j*ld;
  float a0 = 0.f, a1 = 0.f;
  #pragma unroll 4
  for (int i = 0; i < H_; i += 8){
    float4 x = *(const float4*)(wr + i);
    float4 y = *(const float4*)(wr + i + 4);
    a0 += e[i  ]*x.x + e[i+1]*x.y + e[i+2]*x.z + e[i+3]*x.w;
    a1 += e[i+4]*y.x + e[i+5]*y.y + e[i+6]*y.z + e[i+7]*y.w;
  }
  o[v*H_ + j] = a0 + a1 + b[j];
}

// ---- Convert the three K-major 256x256 weight slices to bf16.
__global__ void k_convw(const float* __restrict__ Ur, const float* __restrict__ Wz,
                        const float* __restrict__ Wh,
                        u16* __restrict__ Urb, u16* __restrict__ Wzb, u16* __restrict__ Whb){
  int r = blockIdx.x, j = threadIdx.x;
  Urb[r*H_ + j] = f2b(Ur[r*H_ + j]);
  Wzb[r*H_ + j] = f2b(Wz[r*(2*H_) + H_ + j]);   // columns H..2H of Wz row r
  Whb[r*H_ + j] = f2b(Wh[r*(2*H_) + H_ + j]);
}

// ---- vmsg[m] = fnode[fmess[m]]; h1 closed form (h0=0), bf16, masked at m==0.
__global__ void k_init(const int* __restrict__ fnode, const int* __restrict__ fmess,
                       const float* __restrict__ tWz, const float* __restrict__ tWh,
                       int* __restrict__ vmsg, u16* __restrict__ hb){
  int m = blockIdx.x, j = threadIdx.x;
  int v = fnode[fmess[m]];
  if (j == 0) vmsg[m] = v;
  float val = (m == 0) ? 0.f : sigm(tWz[v*H_ + j])*tanh_(tWh[v*H_ + j]);
  hb[(size_t)m*H_ + j] = f2b(val);
}

// ---- Neighbor gather + reduce from bf16 h: sum_h and sum_gated.
__global__ void k_gather(const u16* __restrict__ hb, const u16* __restrict__ hUr,
                         const int* __restrict__ mg, const int* __restrict__ vmsg,
                         const float* __restrict__ tWr,
                         u16* __restrict__ sumh, u16* __restrict__ sumg){
  int m = blockIdx.x*2 + (threadIdx.x >> 7);
  if (m >= M_) return;
  int tj = (threadIdx.x & 127) * 2;
  int v = vmsg[m];
  float2 xr = *(const float2*)(tWr + v*H_ + tj);
  float s0=0.f, s1=0.f, g0=0.f, g1=0.f;
  #pragma unroll
  for (int k=0;k<K_;k++){
    int g = mg[m*K_ + k];
    u32 hp = *(const u32*)(hb  + (size_t)g*H_ + tj);
    u32 up = *(const u32*)(hUr + (size_t)g*H_ + tj);
    float h0 = b2f((u16)hp), h1 = b2f((u16)(hp>>16));
    float u0 = b2f((u16)up), u1 = b2f((u16)(up>>16));
    s0 += h0; s1 += h1;
    g0 += sigm(xr.x+u0)*h0; g1 += sigm(xr.y+u1)*h1;
  }
  *(u32*)(sumh + (size_t)m*H_ + tj) = (u32)f2b(s0) | ((u32)f2b(s1)<<16);
  *(u32*)(sumg + (size_t)m*H_ + tj) = (u32)f2b(g0) | ((u32)f2b(g1)<<16);
}

// ---- Plain MFMA GEMM (hUr = h @ Ur.T). 128x128 tile, BK=32, XOR-swizzled LDS.
__global__ __launch_bounds__(256,2) void k_gemm(
    const u16* __restrict__ A, const u16* __restrict__ W, u16* __restrict__ C){
  __shared__ __align__(16) u16 lA[128*32];
  __shared__ __align__(16) u16 lB[128*32];
  const int t    = threadIdx.x;
  const int m0   = (blockIdx.x >> 1) * 128;
  const int n0   = (blockIdx.x & 1) * 128;
  const int lane = t & 63, wave = t >> 6;
  const int wrow = wave >> 1, wcol = wave & 1;
  const int l16  = lane & 15, kc8 = lane >> 4;

  f32x4 acc[4][4];
  #pragma unroll
  for (int r=0;r<4;r++)
    #pragma unroll
    for (int c=0;c<4;c++)
      #pragma unroll
      for (int q=0;q<4;q++) acc[r][c][q] = 0.f;

  for (int k0=0; k0<H_; k0+=32){
    __syncthreads();
    #pragma unroll
    for (int p=0;p<2;p++){
      int ch  = t + 256*p;
      int row = ch >> 2, kc = ch & 3;
      int cc  = kc ^ swz(row);
      int gm  = m0 + row;
      uint4 va = (gm < M_) ? *(const uint4*)(A + (size_t)gm*H_ + k0 + kc*8)
                           : make_uint4(0u,0u,0u,0u);
      *(uint4*)(&lA[row*32 + cc*8]) = va;
      uint4 vb = *(const uint4*)(W + (size_t)(n0+row)*H_ + k0 + kc*8);
      *(uint4*)(&lB[row*32 + cc*8]) = vb;
    }
    __syncthreads();
    bf16x8 aF[4], bF[4];
    #pragma unroll
    for (int r=0;r<4;r++){
      int row = wrow*64 + r*16 + l16;
      aF[r] = *(const bf16x8*)(&lA[row*32 + (kc8 ^ swz(row))*8]);
    }
    #pragma unroll
    for (int c=0;c<4;c++){
      int row = wcol*64 + c*16 + l16;
      bF[c] = *(const bf16x8*)(&lB[row*32 + (kc8 ^ swz(row))*8]);
    }
    #pragma unroll
    for (int r=0;r<4;r++)
      #pragma unroll
      for (int c=0;c<4;c++)
        acc[r][c] = __builtin_amdgcn_mfma_f32_16x16x32_bf16(aF[r], bF[c], acc[r][c], 0,0,0);
  }

  #pragma unroll
  for (int r=0;r<4;r++){
    #pragma unroll
    for (int c=0;c<4;c++){
      int mb = m0 + wrow*64 + r*16 + kc8*4;
      int n  = n0 + wcol*64 + c*16 + l16;
      #pragma unroll
      for (int q=0;q<4;q++){
        int m = mb + q;
        if (m < M_) C[(size_t)m*H_ + n] = f2b(acc[r][c][q]);
      }
    }
  }
}

// ---- MERGED dual GEMM + GRU epilogue: zacc = sumh@Wz2.T, hacc = sumg@Wh2.T,
// h' = (1-z)*sumh + z*tanh(xh + hacc), z = sigm(xz + zacc). zlin never hits memory.
template<bool F32OUT>
__global__ __launch_bounds__(256,2) void k_gemmzh(
    const u16* __restrict__ sumh, const u16* __restrict__ sumg,
    const u16* __restrict__ Wzb, const u16* __restrict__ Whb,
    void* __restrict__ Cv,
    const float* __restrict__ tWz, const float* __restrict__ tWh,
    const int* __restrict__ vmsg){
  __shared__ __align__(16) u16 lH[128*32];
  __shared__ __align__(16) u16 lG[128*32];
  __shared__ __align__(16) u16 lZ[128*32];
  __shared__ __align__(16) u16 lW[128*32];
  const int t    = threadIdx.x;
  const int m0   = (blockIdx.x >> 1) * 128;
  const int n0   = (blockIdx.x & 1) * 128;
  const int lane = t & 63, wave = t >> 6;
  const int wrow = wave >> 1, wcol = wave & 1;
  const int l16  = lane & 15, kc8 = lane >> 4;

  f32x4 accZ[4][4], accH[4][4];
  #pragma unroll
  for (int r=0;r<4;r++)
    #pragma unroll
    for (int c=0;c<4;c++)
      #pragma unroll
      for (int q=0;q<4;q++){ accZ[r][c][q] = 0.f; accH[r][c][q] = 0.f; }

  for (int k0=0; k0<H_; k0+=32){
    __syncthreads();
    #pragma unroll
    for (int p=0;p<2;p++){
      int ch  = t + 256*p;
      int row = ch >> 2, kc = ch & 3;
      int cc  = kc ^ swz(row);
      int gm  = m0 + row;
      uint4 vh = make_uint4(0u,0u,0u,0u), vg = vh;
      if (gm < M_){
        vh = *(const uint4*)(sumh + (size_t)gm*H_ + k0 + kc*8);
        vg = *(const uint4*)(sumg + (size_t)gm*H_ + k0 + kc*8);
      }
      uint4 vz = *(const uint4*)(Wzb + (size_t)(n0+row)*H_ + k0 + kc*8);
      uint4 vw = *(const uint4*)(Whb + (size_t)(n0+row)*H_ + k0 + kc*8);
      *(uint4*)(&lH[row*32 + cc*8]) = vh;
      *(uint4*)(&lG[row*32 + cc*8]) = vg;
      *(uint4*)(&lZ[row*32 + cc*8]) = vz;
      *(uint4*)(&lW[row*32 + cc*8]) = vw;
    }
    __syncthreads();
    #pragma unroll
    for (int r=0;r<4;r++){
      int arow = wrow*64 + r*16 + l16;
      int aoff = arow*32 + ((kc8 ^ swz(arow))*8);
      bf16x8 aH = *(const bf16x8*)(&lH[aoff]);
      bf16x8 aG = *(const bf16x8*)(&lG[aoff]);
      #pragma unroll
      for (int c=0;c<4;c++){
        int brow = wcol*64 + c*16 + l16;
        int boff = brow*32 + ((kc8 ^ swz(brow))*8);
        bf16x8 bZ = *(const bf16x8*)(&lZ[boff]);
        bf16x8 bW = *(const bf16x8*)(&lW[boff]);
        accZ[r][c] = __builtin_amdgcn_mfma_f32_16x16x32_bf16(aH, bZ, accZ[r][c], 0,0,0);
        accH[r][c] = __builtin_amdgcn_mfma_f32_16x16x32_bf16(aG, bW, accH[r][c], 0,0,0);
      }
    }
  }

  #pragma unroll
  for (int r=0;r<4;r++){
    #pragma unroll
    for (int c=0;c<4;c++){
      int mb = m0 + wrow*64 + r*16 + kc8*4;     // C/D: row=(lane>>4)*4+reg
      int n  = n0 + wcol*64 + c*16 + l16;       //      col=lane&15
      #pragma unroll
      for (int q=0;q<4;q++){
        int m = mb + q;
        if (m < M_){
          int v = vmsg[m];
          float z   = sigm(tWz[v*H_ + n] + accZ[r][c][q]);
          float pre = tanh_(tWh[v*H_ + n] + accH[r][c][q]);
          float sh  = b2f(sumh[(size_t)m*H_ + n]);
          float o   = (m == 0) ? 0.f : (1.f - z)*sh + z*pre;
          if (F32OUT) ((float*)Cv)[(size_t)m*H_ + n] = o;
          else        ((u16*)Cv)[(size_t)m*H_ + n] = f2b(o);
        }
      }
    }
  }
}

// ---- Readout: only B=64 scope rows are needed. h f32 (final), out f32.
__global__ void k_final(const float* __restrict__ h, const int* __restrict__ ng,
                        const int* __restrict__ fnode, const int* __restrict__ scope,
                        const float* __restrict__ tWo, const float* __restrict__ Wo,
                        float* __restrict__ out){
  int b = blockIdx.x, j = threadIdx.x;
  int n = scope[b];
  __shared__ float mn[H_];
  float s = 0.f;
  #pragma unroll
  for (int k=0;k<K_;k++){
    int g = ng[n*K_ + k];
    s += h[(size_t)g*H_ + j];
  }
  mn[j] = s;
  __syncthreads();
  int v = fnode[n];
  float acc = tWo[v*H_ + j];
  const float* w = Wo + j*(2*H_) + H_;
  for (int i=0;i<H_;i+=4){
    float4 a = *(const float4*)(w+i);
    acc += mn[i]*a.x + mn[i+1]*a.y + mn[i+2]*a.z + mn[i+3]*a.w;
  }
  out[b*H_ + j] = fmaxf(acc, 0.f);
}

// ---- Guard signal: all-zero f32 output.
__global__ void k_zero(float* __restrict__ out, int n){
  int i = blockIdx.x*256 + threadIdx.x;
  int stride = gridDim.x*256;
  for (; i < n; i += stride) out[i] = 0.f;
}

extern "C" void kernel_launch(void* const* d_in, const int* in_sizes, int n_in,
                              void* d_out, int out_size, void* d_ws, size_t ws_size,
                              hipStream_t stream){
  const int* fnode      = (const int*)d_in[0];
  const int* fmess      = (const int*)d_in[1];
  const int* node_graph = (const int*)d_in[2];
  const int* mess_graph = (const int*)d_in[3];
  const int* scope_st   = (const int*)d_in[4];
  const float* emb = (const float*)d_in[5];
  const float* Wz  = (const float*)d_in[6];
  const float* bz  = (const float*)d_in[7];
  const float* Wr  = (const float*)d_in[8];
  const float* Ur  = (const float*)d_in[9];
  const float* bu  = (const float*)d_in[10];
  const float* Wh  = (const float*)d_in[11];
  const float* bh  = (const float*)d_in[12];
  const float* Wo  = (const float*)d_in[13];
  const float* bo  = (const float*)d_in[14];

  char* ws = (char*)d_ws;
  size_t off = 0;
  float* tWz = (float*)(ws + off); off += (size_t)V_*H_*4;
  float* tWr = (float*)(ws + off); off += (size_t)V_*H_*4;
  float* tWh = (float*)(ws + off); off += (size_t)V_*H_*4;
  float* tWo = (float*)(ws + off); off += (size_t)V_*H_*4;
  u16* Urb  = (u16*)(ws + off); off += (size_t)H_*H_*2;
  u16* Wzb  = (u16*)(ws + off); off += (size_t)H_*H_*2;
  u16* Whb  = (u16*)(ws + off); off += (size_t)H_*H_*2;
  int* vmsg = (int*)(ws + off); off += ((size_t)M_*4 + 511) & ~(size_t)511;
  u16* hUr  = (u16*)(ws + off); off += (size_t)M_*H_*2;
  u16* sumh = (u16*)(ws + off); off += (size_t)M_*H_*2;
  u16* sumg = (u16*)(ws + off); off += (size_t)M_*H_*2;

  if (ws_size < off){
    k_zero<<<2048, 256, 0, stream>>>((float*)d_out, out_size);
    return;
  }

  float* out = (float*)d_out;          // output dtype f32 (established R6)
  float* h   = out + (size_t)B_*H_;    // h (output 1) lives in d_out, f32
  u16*   hb  = (u16*)h;                // bf16 shadow of h during iterations

  const int MT = (M_ + 127)/128;       // 782 row tiles
  const int GG = 2*MT;                 // x2 col tiles

  k_tables<<<dim3(V_,4), H_, 0, stream>>>(emb, Wz, bz, Wr, bu, Wh, bh, Wo, bo,
                                          tWz, tWr, tWh, tWo);
  k_convw<<<H_, H_, 0, stream>>>(Ur, Wz, Wh, Urb, Wzb, Whb);
  k_init<<<M_, H_, 0, stream>>>(fnode, fmess, tWz, tWh, vmsg, hb);

  for (int it = 0; it < DEPTH_-1; ++it){
    // hUr = h @ Ur.T
    k_gemm<<<GG, 256, 0, stream>>>(hb, Urb, hUr);
    // sum_h, sum_gated (reads bf16 hb)
    k_gather<<<(M_+1)/2, 256, 0, stream>>>(hb, hUr, mess_graph, vmsg, tWr, sumh, sumg);
    // merged: z-GEMM + h-GEMM + GRU update; mid iters -> bf16 hb, final -> f32 h
    if (it < DEPTH_-2)
      k_gemmzh<false><<<GG, 256, 0, stream>>>(sumh, sumg, Wzb, Whb, hb,
                                              tWz, tWh, vmsg);
    else
      k_gemmzh<true ><<<GG, 256, 0, stream>>>(sumh, sumg, Wzb, Whb, h,
                                              tWz, tWh, vmsg);
  }

  k_final<<<B_, H_, 0, stream>>>(h, node_graph, fnode, scope_st, tWo, Wo, out);
}

// Round 10
// 1674.025 us; speedup vs baseline: 4.5144x; 1.0448x over previous
//
#include <hip/hip_runtime.h>

typedef unsigned short u16;
typedef unsigned int   u32;
typedef short bf16x8 __attribute__((ext_vector_type(8)));
typedef float f32x4  __attribute__((ext_vector_type(4)));

#define V_ 780
#define N_ 50000
#define M_ 100001
#define K_ 6
#define H_ 256
#define B_ 64
#define DEPTH_ 6

typedef __attribute__((address_space(3))) u32 lds_u32;
typedef __attribute__((address_space(1))) const u32 glb_u32;
__device__ __forceinline__ void dma16(const void* g, void* l){
  __builtin_amdgcn_global_load_lds((glb_u32*)g, (lds_u32*)l, 16, 0, 0);
}

__device__ __forceinline__ float b2f(u16 u){
  union { u32 i; float f; } x; x.i = ((u32)u) << 16; return x.f;
}
__device__ __forceinline__ u16 f2b(float f){
  union { float f; u32 i; } x; x.f = f;
  u32 r = x.i + 0x7fffu + ((x.i >> 16) & 1u);   // RNE
  return (u16)(r >> 16);
}
__device__ __forceinline__ float sigm(float x){ return 1.f/(1.f + __expf(-x)); }
__device__ __forceinline__ float tanh_(float x){
  x = fminf(fmaxf(x, -15.f), 15.f);
  float e = __expf(2.f*x);
  return (e - 1.f)/(e + 1.f);
}
__device__ __forceinline__ int swz(int r){ return (r + (r >> 2)) & 3; }

// ---- Per-vocab tables, f32-exact. Grid (V, 4): block = (vocab v, matrix q).
__global__ void k_tables(const float* __restrict__ emb,
    const float* __restrict__ Wz, const float* __restrict__ bz,
    const float* __restrict__ Wr, const float* __restrict__ bu,
    const float* __restrict__ Wh, const float* __restrict__ bh,
    const float* __restrict__ Wo, const float* __restrict__ bo,
    float* __restrict__ tWz, float* __restrict__ tWr,
    float* __restrict__ tWh, float* __restrict__ tWo){
  int v = blockIdx.x, q = blockIdx.y, j = threadIdx.x;
  __shared__ float e[H_];
  e[j] = emb[v*H_ + j];
  __syncthreads();
  const float* w; const float* b; float* o; int ld;
  if      (q == 0){ w = Wz; b = bz; o = tWz; ld = 2*H_; }
  else if (q == 1){ w = Wr; b = bu; o = tWr; ld = H_;   }
  else if (q == 2){ w = Wh; b = bh; o = tWh; ld = 2*H_; }
  else            { w = Wo; b = bo; o = tWo; ld = 2*H_; }
  const float* wr = w + (size_t)j*ld;
  float a0 = 0.f, a1 = 0.f;
  #pragma unroll 4
  for (int i = 0; i < H_; i += 8){
    float4 x = *(const float4*)(wr + i);
    float4 y = *(const float4*)(wr + i + 4);
    a0 += e[i  ]*x.x + e[i+1]*x.y + e[i+2]*x.z + e[i+3]*x.w;
    a1 += e[i+4]*y.x + e[i+5]*y.y + e[i+6]*y.z + e[i+7]*y.w;
  }
  o[v*H_ + j] = a0 + a1 + b[j];
}

// ---- Convert the three K-major 256x256 weight slices to bf16.
__global__ void k_convw(const float* __restrict__ Ur, const float* __restrict__ Wz,
                        const float* __restrict__ Wh,
                        u16* __restrict__ Urb, u16* __restrict__ Wzb, u16* __restrict__ Whb){
  int r = blockIdx.x, j = threadIdx.x;
  Urb[r*H_ + j] = f2b(Ur[r*H_ + j]);
  Wzb[r*H_ + j] = f2b(Wz[r*(2*H_) + H_ + j]);   // columns H..2H of Wz row r
  Whb[r*H_ + j] = f2b(Wh[r*(2*H_) + H_ + j]);
}

// ---- vmsg[m] = fnode[fmess[m]]; h1 closed form (h0=0), bf16, masked at m==0.
__global__ void k_init(const int* __restrict__ fnode, const int* __restrict__ fmess,
                       const float* __restrict__ tWz, const float* __restrict__ tWh,
                       int* __restrict__ vmsg, u16* __restrict__ hb){
  int m = blockIdx.x, j = threadIdx.x;
  int v = fnode[fmess[m]];
  if (j == 0) vmsg[m] = v;
  float val = (m == 0) ? 0.f : sigm(tWz[v*H_ + j])*tanh_(tWh[v*H_ + j]);
  hb[(size_t)m*H_ + j] = f2b(val);
}

// ---- Neighbor gather + reduce from bf16 h: sum_h and sum_gated.
__global__ void k_gather(const u16* __restrict__ hb, const u16* __restrict__ hUr,
                         const int* __restrict__ mg, const int* __restrict__ vmsg,
                         const float* __restrict__ tWr,
                         u16* __restrict__ sumh, u16* __restrict__ sumg){
  int m = blockIdx.x*2 + (threadIdx.x >> 7);
  if (m >= M_) return;
  int tj = (threadIdx.x & 127) * 2;
  int v = vmsg[m];
  float2 xr = *(const float2*)(tWr + v*H_ + tj);
  float s0=0.f, s1=0.f, g0=0.f, g1=0.f;
  #pragma unroll
  for (int k=0;k<K_;k++){
    int g = mg[m*K_ + k];
    u32 hp = *(const u32*)(hb  + (size_t)g*H_ + tj);
    u32 up = *(const u32*)(hUr + (size_t)g*H_ + tj);
    float h0 = b2f((u16)hp), h1 = b2f((u16)(hp>>16));
    float u0 = b2f((u16)up), u1 = b2f((u16)(up>>16));
    s0 += h0; s1 += h1;
    g0 += sigm(xr.x+u0)*h0; g1 += sigm(xr.y+u1)*h1;
  }
  *(u32*)(sumh + (size_t)m*H_ + tj) = (u32)f2b(s0) | ((u32)f2b(s1)<<16);
  *(u32*)(sumg + (size_t)m*H_ + tj) = (u32)f2b(g0) | ((u32)f2b(g1)<<16);
}

// ---- hUr = h @ Ur.T. 512 threads, BM=128, BN=256 (A staged ONCE), BK=32.
// Staging via global_load_lds width-16: LDS slot fixed (wave base + lane*16),
// XOR swizzle folded into the per-lane GLOBAL address -> LDS image identical to R9.
__global__ __launch_bounds__(512,4) void k_gemm(
    const u16* __restrict__ A, const u16* __restrict__ W, u16* __restrict__ C){
  __shared__ __align__(16) u16 lA[128*32];
  __shared__ __align__(16) u16 lB[256*32];
  const int t    = threadIdx.x;
  const int m0   = blockIdx.x * 128;
  const int lane = t & 63, wave = t >> 6;     // 8 waves: 2 x 4
  const int wrow = wave >> 2, wcol = wave & 3;
  const int l16  = lane & 15, kc8 = lane >> 4;

  // A: 512 slots, 1/thread. slot s=(row,cc): global chunk kc = cc ^ swz(row).
  const int rA = t >> 2, cA = t & 3;
  const int kA = (cA ^ swz(rA)) * 8;
  const int gmA = (m0 + rA < M_) ? (m0 + rA) : (M_ - 1);
  u16* const dA = lA + (size_t)(wave*64)*8;   // wave-uniform LDS base
  // B: 1024 slots, 2/thread.
  int rB[2], kB[2];
  u16* dB[2];
  #pragma unroll
  for (int p=0;p<2;p++){
    int s = t + 512*p;
    rB[p] = s >> 2; int cB = s & 3;
    kB[p] = (cB ^ swz(rB[p])) * 8;
    dB[p] = lB + (size_t)(wave*64 + 512*p)*8;
  }

  f32x4 acc[4][4];
  #pragma unroll
  for (int r=0;r<4;r++)
    #pragma unroll
    for (int c=0;c<4;c++)
      #pragma unroll
      for (int q=0;q<4;q++) acc[r][c][q] = 0.f;

  for (int k0=0; k0<H_; k0+=32){
    __syncthreads();
    dma16(A + (size_t)gmA*H_ + k0 + kA, dA);
    #pragma unroll
    for (int p=0;p<2;p++)
      dma16(W + (size_t)rB[p]*H_ + k0 + kB[p], dB[p]);
    __syncthreads();                          // drains vmcnt -> DMA complete
    bf16x8 aF[4], bF[4];
    #pragma unroll
    for (int r=0;r<4;r++){
      int row = wrow*64 + r*16 + l16;
      aF[r] = *(const bf16x8*)(&lA[row*32 + ((kc8 ^ swz(row))*8)]);
    }
    #pragma unroll
    for (int c=0;c<4;c++){
      int row = wcol*64 + c*16 + l16;
      bF[c] = *(const bf16x8*)(&lB[row*32 + ((kc8 ^ swz(row))*8)]);
    }
    #pragma unroll
    for (int r=0;r<4;r++)
      #pragma unroll
      for (int c=0;c<4;c++)
        acc[r][c] = __builtin_amdgcn_mfma_f32_16x16x32_bf16(aF[r], bF[c], acc[r][c], 0,0,0);
  }

  #pragma unroll
  for (int r=0;r<4;r++){
    #pragma unroll
    for (int c=0;c<4;c++){
      int mb = m0 + wrow*64 + r*16 + kc8*4;   // C/D: row=(lane>>4)*4+reg
      int n  = wcol*64 + c*16 + l16;          //      col=lane&15
      #pragma unroll
      for (int q=0;q<4;q++){
        int m = mb + q;
        if (m < M_) C[(size_t)m*H_ + n] = f2b(acc[r][c][q]);
      }
    }
  }
}

// ---- MERGED dual GEMM + GRU epilogue, DMA staging. 256 threads, BM=128, BN=128.
template<bool F32OUT>
__global__ __launch_bounds__(256,2) void k_gemmzh(
    const u16* __restrict__ sumh, const u16* __restrict__ sumg,
    const u16* __restrict__ Wzb, const u16* __restrict__ Whb,
    void* __restrict__ Cv,
    const float* __restrict__ tWz, const float* __restrict__ tWh,
    const int* __restrict__ vmsg){
  __shared__ __align__(16) u16 lH[128*32];
  __shared__ __align__(16) u16 lG[128*32];
  __shared__ __align__(16) u16 lZ[128*32];
  __shared__ __align__(16) u16 lW[128*32];
  const int t    = threadIdx.x;
  const int m0   = (blockIdx.x >> 1) * 128;
  const int n0   = (blockIdx.x & 1) * 128;
  const int lane = t & 63, wave = t >> 6;
  const int wrow = wave >> 1, wcol = wave & 1;
  const int l16  = lane & 15, kc8 = lane >> 4;

  // 512 slots per matrix, 2/thread each.
  int rS[2], kS[2];
  size_t bOff[2];
  #pragma unroll
  for (int p=0;p<2;p++){
    int s = t + 256*p;
    rS[p] = s >> 2; int cc = s & 3;
    kS[p] = (cc ^ swz(rS[p])) * 8;
    bOff[p] = (size_t)(wave*64 + 256*p)*8;
  }
  int gmS[2];
  #pragma unroll
  for (int p=0;p<2;p++) gmS[p] = (m0 + rS[p] < M_) ? (m0 + rS[p]) : (M_ - 1);

  f32x4 accZ[4][4], accH[4][4];
  #pragma unroll
  for (int r=0;r<4;r++)
    #pragma unroll
    for (int c=0;c<4;c++)
      #pragma unroll
      for (int q=0;q<4;q++){ accZ[r][c][q] = 0.f; accH[r][c][q] = 0.f; }

  for (int k0=0; k0<H_; k0+=32){
    __syncthreads();
    #pragma unroll
    for (int p=0;p<2;p++){
      dma16(sumh + (size_t)gmS[p]*H_ + k0 + kS[p],        lH + bOff[p]);
      dma16(sumg + (size_t)gmS[p]*H_ + k0 + kS[p],        lG + bOff[p]);
      dma16(Wzb  + (size_t)(n0+rS[p])*H_ + k0 + kS[p],    lZ + bOff[p]);
      dma16(Whb  + (size_t)(n0+rS[p])*H_ + k0 + kS[p],    lW + bOff[p]);
    }
    __syncthreads();
    #pragma unroll
    for (int r=0;r<4;r++){
      int arow = wrow*64 + r*16 + l16;
      int aoff = arow*32 + ((kc8 ^ swz(arow))*8);
      bf16x8 aH = *(const bf16x8*)(&lH[aoff]);
      bf16x8 aG = *(const bf16x8*)(&lG[aoff]);
      #pragma unroll
      for (int c=0;c<4;c++){
        int brow = wcol*64 + c*16 + l16;
        int boff = brow*32 + ((kc8 ^ swz(brow))*8);
        bf16x8 bZ = *(const bf16x8*)(&lZ[boff]);
        bf16x8 bW = *(const bf16x8*)(&lW[boff]);
        accZ[r][c] = __builtin_amdgcn_mfma_f32_16x16x32_bf16(aH, bZ, accZ[r][c], 0,0,0);
        accH[r][c] = __builtin_amdgcn_mfma_f32_16x16x32_bf16(aG, bW, accH[r][c], 0,0,0);
      }
    }
  }

  #pragma unroll
  for (int r=0;r<4;r++){
    #pragma unroll
    for (int c=0;c<4;c++){
      int mb = m0 + wrow*64 + r*16 + kc8*4;     // C/D: row=(lane>>4)*4+reg
      int n  = n0 + wcol*64 + c*16 + l16;       //      col=lane&15
      #pragma unroll
      for (int q=0;q<4;q++){
        int m = mb + q;
        if (m < M_){
          int v = vmsg[m];
          float z   = sigm(tWz[v*H_ + n] + accZ[r][c][q]);
          float pre = tanh_(tWh[v*H_ + n] + accH[r][c][q]);
          float sh  = b2f(sumh[(size_t)m*H_ + n]);
          float o   = (m == 0) ? 0.f : (1.f - z)*sh + z*pre;
          if (F32OUT) ((float*)Cv)[(size_t)m*H_ + n] = o;
          else        ((u16*)Cv)[(size_t)m*H_ + n] = f2b(o);
        }
      }
    }
  }
}

// ---- Readout: only B=64 scope rows are needed. h f32 (final), out f32.
__global__ void k_final(const float* __restrict__ h, const int* __restrict__ ng,
                        const int* __restrict__ fnode, const int* __restrict__ scope,
                        const float* __restrict__ tWo, const float* __restrict__ Wo,
                        float* __restrict__ out){
  int b = blockIdx.x, j = threadIdx.x;
  int n = scope[b];
  __shared__ float mn[H_];
  float s = 0.f;
  #pragma unroll
  for (int k=0;k<K_;k++){
    int g = ng[n*K_ + k];
    s += h[(size_t)g*H_ + j];
  }
  mn[j] = s;
  __syncthreads();
  int v = fnode[n];
  float acc = tWo[v*H_ + j];
  const float* w = Wo + j*(2*H_) + H_;
  for (int i=0;i<H_;i+=4){
    float4 a = *(const float4*)(w+i);
    acc += mn[i]*a.x + mn[i+1]*a.y + mn[i+2]*a.z + mn[i+3]*a.w;
  }
  out[b*H_ + j] = fmaxf(acc, 0.f);
}

// ---- Guard signal: all-zero f32 output.
__global__ void k_zero(float* __restrict__ out, int n){
  int i = blockIdx.x*256 + threadIdx.x;
  int stride = gridDim.x*256;
  for (; i < n; i += stride) out[i] = 0.f;
}

extern "C" void kernel_launch(void* const* d_in, const int* in_sizes, int n_in,
                              void* d_out, int out_size, void* d_ws, size_t ws_size,
                              hipStream_t stream){
  const int* fnode      = (const int*)d_in[0];
  const int* fmess      = (const int*)d_in[1];
  const int* node_graph = (const int*)d_in[2];
  const int* mess_graph = (const int*)d_in[3];
  const int* scope_st   = (const int*)d_in[4];
  const float* emb = (const float*)d_in[5];
  const float* Wz  = (const float*)d_in[6];
  const float* bz  = (const float*)d_in[7];
  const float* Wr  = (const float*)d_in[8];
  const float* Ur  = (const float*)d_in[9];
  const float* bu  = (const float*)d_in[10];
  const float* Wh  = (const float*)d_in[11];
  const float* bh  = (const float*)d_in[12];
  const float* Wo  = (const float*)d_in[13];
  const float* bo  = (const float*)d_in[14];

  char* ws = (char*)d_ws;
  size_t off = 0;
  float* tWz = (float*)(ws + off); off += (size_t)V_*H_*4;
  float* tWr = (float*)(ws + off); off += (size_t)V_*H_*4;
  float* tWh = (float*)(ws + off); off += (size_t)V_*H_*4;
  float* tWo = (float*)(ws + off); off += (size_t)V_*H_*4;
  u16* Urb  = (u16*)(ws + off); off += (size_t)H_*H_*2;
  u16* Wzb  = (u16*)(ws + off); off += (size_t)H_*H_*2;
  u16* Whb  = (u16*)(ws + off); off += (size_t)H_*H_*2;
  int* vmsg = (int*)(ws + off); off += ((size_t)M_*4 + 511) & ~(size_t)511;
  u16* hUr  = (u16*)(ws + off); off += (size_t)M_*H_*2;
  u16* sumh = (u16*)(ws + off); off += (size_t)M_*H_*2;
  u16* sumg = (u16*)(ws + off); off += (size_t)M_*H_*2;

  if (ws_size < off){
    k_zero<<<2048, 256, 0, stream>>>((float*)d_out, out_size);
    return;
  }

  float* out = (float*)d_out;          // output dtype f32 (established R6)
  float* h   = out + (size_t)B_*H_;    // h (output 1) lives in d_out, f32
  u16*   hb  = (u16*)h;                // bf16 shadow of h during iterations

  const int MT = (M_ + 127)/128;       // 782 row tiles
  const int GG = 2*MT;                 // gemmzh: x2 col tiles

  k_tables<<<dim3(V_,4), H_, 0, stream>>>(emb, Wz, bz, Wr, bu, Wh, bh, Wo, bo,
                                          tWz, tWr, tWh, tWo);
  k_convw<<<H_, H_, 0, stream>>>(Ur, Wz, Wh, Urb, Wzb, Whb);
  k_init<<<M_, H_, 0, stream>>>(fnode, fmess, tWz, tWh, vmsg, hb);

  for (int it = 0; it < DEPTH_-1; ++it){
    // hUr = h @ Ur.T  (BN=256: one block covers all cols, A staged once)
    k_gemm<<<MT, 512, 0, stream>>>(hb, Urb, hUr);
    // sum_h, sum_gated (reads bf16 hb)
    k_gather<<<(M_+1)/2, 256, 0, stream>>>(hb, hUr, mess_graph, vmsg, tWr, sumh, sumg);
    // merged: z-GEMM + h-GEMM + GRU update; mid iters -> bf16 hb, final -> f32 h
    if (it < DEPTH_-2)
      k_gemmzh<false><<<GG, 256, 0, stream>>>(sumh, sumg, Wzb, Whb, hb,
                                              tWz, tWh, vmsg);
    else
      k_gemmzh<true ><<<GG, 256, 0, stream>>>(sumh, sumg, Wzb, Whb, h,
                                              tWz, tWh, vmsg);
  }

  k_final<<<B_, H_, 0, stream>>>(h, node_graph, fnode, scope_st, tWo, Wo, out);
}